// Round 1
// 66.320 us; speedup vs baseline: 1.0081x; 1.0081x over previous
//
#include <hip/hip_runtime.h>

// Problem constants: B=8, k=8 bits, H=W=64 -> N=4096, d_v=32.
#define B_SZ   8
#define KBITS  8
#define NPOS   4096
#define DV     32
#define NCODE  256
#define NSLICE 32              // n-slices per batch; 256 blocks total

// ---------------------------------------------------------------------------
// Two-kernel split: the 256x32 value table depends only on (batch, temp), but
// the old single kernel recomputed it in all 32 slice-blocks per batch
// (32x redundant z reads, code packs, histogram atomics). Split at the
// histogram reduction:
//   k1: per-slice code packing + per-block partial histogram (fully
//       overwritten -> no dependency on poisoned workspace contents).
//   k2: sum 32 partials -> butterfly table (cheap, in-register) -> gather.
// Workspace layout: codes (8*1024 u32 = 32 KB) | partial (256*256 i32 = 256 KB).
// ---------------------------------------------------------------------------

__global__ __launch_bounds__(256) void k_codes(const float* __restrict__ z,
                                               unsigned int* __restrict__ codes_g,
                                               int* __restrict__ partial_g) {
    const int blk = blockIdx.x;
    const int b   = blk >> 5;            // batch
    const int s   = blk & (NSLICE - 1);  // slice of 128 positions
    const int t   = threadIdx.x;

    __shared__ int h[NCODE];
    h[t] = 0;
    __syncthreads();

    // thread t: position-group j = t>>3 (4 consecutive positions), bit = t&7.
    // One float4 load per thread; OR-reduce the 8 bit-planes across the
    // 8-lane group via shfl_xor (groups are contiguous in the wave).
    const int j   = t >> 3;
    const int bit = t & 7;
    const float4 f = ((const float4*)z)[b * (KBITS * NPOS / 4) +
                                        bit * (NPOS / 4) + s * 32 + j];
    unsigned int p = ((unsigned)(f.x > 0.5f) << bit)
                   | ((unsigned)(f.y > 0.5f) << (8  + bit))
                   | ((unsigned)(f.z > 0.5f) << (16 + bit))
                   | ((unsigned)(f.w > 0.5f) << (24 + bit));
    p |= __shfl_xor(p, 1);
    p |= __shfl_xor(p, 2);
    p |= __shfl_xor(p, 4);

    if (bit == 0) {
        codes_g[b * (NPOS / 4) + s * 32 + j] = p;   // packed 4 codes / u32
        atomicAdd(&h[p & 255], 1);
        atomicAdd(&h[(p >> 8) & 255], 1);
        atomicAdd(&h[(p >> 16) & 255], 1);
        atomicAdd(&h[p >> 24], 1);
    }
    __syncthreads();

    partial_g[blk * NCODE + t] = h[t];   // full overwrite, no init needed
}

// ---------------------------------------------------------------------------
// k2: block (b, s). Sum partial histograms, rebuild table (in-register
// butterfly, identical math to previous version), gather own 128 positions.
// ---------------------------------------------------------------------------
__global__ __launch_bounds__(1024) void k_table(const unsigned int* __restrict__ codes_g,
                                                const int* __restrict__ partial_g,
                                                const float* __restrict__ V,
                                                const float* __restrict__ temp,
                                                float* __restrict__ out) {
    const int b   = blockIdx.x >> 5;
    const int s   = blockIdx.x & (NSLICE - 1);
    const int tid = threadIdx.x;

    __shared__ int   h[NCODE];                 // 1 KB
    __shared__ float T[NCODE * (DV + 1)];      // 33.8 KB, stride 33

    if (tid < NCODE) h[tid] = 0;
    __syncthreads();

    // ---- sum the batch's 32 partial histograms (L2-resident, coalesced) ----
    {
        const int bin = tid & 255;
        const int q   = tid >> 8;              // 4 groups x 8 slices each
        const int* pg = partial_g + (b * NSLICE + q * 8) * NCODE + bin;
        int sum = 0;
#pragma unroll
        for (int i = 0; i < 8; ++i) sum += pg[i * NCODE];
        atomicAdd(&h[bin], sum);
    }
    __syncthreads();

    // ---- per-lane seeds: half-wave hw = tid>>5 owns d-column, lane l owns
    //      codes v = 8l..8l+7 ----
    const int d = tid >> 5;
    const int l = tid & 31;
    const float a = __expf(-1.0f / fmaxf(temp[0], 0.1f));

    float val[8], cnt[8];
#pragma unroll
    for (int j = 0; j < 8; ++j) {
        const int v = l * 8 + j;
        const float c = (float)h[v];
        cnt[j] = c;
        val[j] = c * V[v * DV + d];            // V is 32 KB -> cache-resident
    }

    // ---- butterfly stages 0..2 in registers ----
#pragma unroll
    for (int st = 0; st < 3; ++st) {
        const int m = 1 << st;
#pragma unroll
        for (int j = 0; j < 8; ++j) {
            if ((j & m) == 0) {
                const int j1 = j | m;
                const float v0 = val[j], v1 = val[j1];
                val[j]  = fmaf(a, v1, v0);
                val[j1] = fmaf(a, v0, v1);
                const float s0 = cnt[j], s1 = cnt[j1];
                cnt[j]  = fmaf(a, s1, s0);
                cnt[j1] = fmaf(a, s0, s1);
            }
        }
    }
    // ---- stages 3..7 via shuffle (masks 1..16 stay inside half-wave) ----
#pragma unroll
    for (int st = 0; st < 5; ++st) {
        const int m = 1 << st;
#pragma unroll
        for (int j = 0; j < 8; ++j) {
            const float pv = __shfl_xor(val[j], m);
            val[j] = fmaf(a, pv, val[j]);
            const float pc = __shfl_xor(cnt[j], m);
            cnt[j] = fmaf(a, pc, cnt[j]);
        }
    }

    // ---- normalize lane-locally, write table to LDS ----
#pragma unroll
    for (int j = 0; j < 8; ++j) {
        const int c = l * 8 + j;
        T[c * (DV + 1) + d] = val[j] / cnt[j];
    }
    __syncthreads();

    // ---- gather own slice: one float4 store per thread ----
    {
        const int ng   = tid & 31;                 // float4 index within slice
        const int base = s * 128 + ng * 4;         // n offset of this float4
        const unsigned int cw = codes_g[b * (NPOS / 4) + s * 32 + ng];
        float4 r;
        r.x = T[(cw         & 255) * (DV + 1) + d];
        r.y = T[((cw >> 8)  & 255) * (DV + 1) + d];
        r.z = T[((cw >> 16) & 255) * (DV + 1) + d];
        r.w = T[(cw >> 24)         * (DV + 1) + d];
        float4* o4 = (float4*)(out + (size_t)(b * DV + d) * NPOS + base);
        *o4 = r;
    }
}

// ---------------------------------------------------------------------------
extern "C" void kernel_launch(void* const* d_in, const int* in_sizes, int n_in,
                              void* d_out, int out_size, void* d_ws, size_t ws_size,
                              hipStream_t stream) {
    const float* z    = (const float*)d_in[0];   // (B,8,64,64) fp32
    const float* temp = (const float*)d_in[1];   // scalar
    const float* V    = (const float*)d_in[2];   // (256,32) fp32
    float* out        = (float*)d_out;           // (B,32,64,64) fp32

    unsigned int* codes_g = (unsigned int*)d_ws;                    // 32 KB
    int* partial_g        = (int*)d_ws + B_SZ * (NPOS / 4);         // 256 KB

    k_codes<<<B_SZ * NSLICE, 256, 0, stream>>>(z, codes_g, partial_g);
    k_table<<<B_SZ * NSLICE, 1024, 0, stream>>>(codes_g, partial_g, V, temp, out);
}

// Round 2
// 65.611 us; speedup vs baseline: 1.0190x; 1.0108x over previous
//
#include <hip/hip_runtime.h>

// Problem constants: B=8, k=8 bits, H=W=64 -> N=4096, d_v=32.
#define B_SZ   8
#define KBITS  8
#define NPOS   4096
#define DV     32
#define NCODE  256
#define NSLICE 32              // n-slices per batch; 256 blocks total

// ---------------------------------------------------------------------------
// k1: per-slice code packing + per-block partial histogram (fully overwritten
//     -> no dependency on poisoned workspace contents).
// k2: sum partials -> butterfly table -> gather. This round attacks k2's
//     per-block critical path (the only thing that matters at 1 block/CU):
//       * cnt/S butterfly deduplicated: one half-wave computes it, publishes
//         Sinv[256]; everyone else only runs the val butterfly (DS shuffle
//         ops 1280 -> ~680 per block). Normalize folded into gather multiply
//         (8 divisions/thread -> 8 rcp in 32 threads).
//       * histogram reads padded hf[v + (v>>3)] -> seed addr 9l+j, gcd(9,32)=1,
//         conflict-free (was 16-way).
//       * T swizzled idx(c,d) = (c<<5) + (d ^ (c>>3)) -> write bank d^l all
//         distinct, conflict-free (was 16-way); gather reads ~2-way random.
//       * histogram sum via plain hq[4][256] partials, no LDS atomics.
// ---------------------------------------------------------------------------

__global__ __launch_bounds__(256) void k_codes(const float* __restrict__ z,
                                               unsigned int* __restrict__ codes_g,
                                               int* __restrict__ partial_g) {
    const int blk = blockIdx.x;
    const int b   = blk >> 5;            // batch
    const int s   = blk & (NSLICE - 1);  // slice of 128 positions
    const int t   = threadIdx.x;

    __shared__ int h[NCODE];
    h[t] = 0;
    __syncthreads();

    // thread t: position-group j = t>>3 (4 consecutive positions), bit = t&7.
    const int j   = t >> 3;
    const int bit = t & 7;
    const float4 f = ((const float4*)z)[b * (KBITS * NPOS / 4) +
                                        bit * (NPOS / 4) + s * 32 + j];
    unsigned int p = ((unsigned)(f.x > 0.5f) << bit)
                   | ((unsigned)(f.y > 0.5f) << (8  + bit))
                   | ((unsigned)(f.z > 0.5f) << (16 + bit))
                   | ((unsigned)(f.w > 0.5f) << (24 + bit));
    p |= __shfl_xor(p, 1);
    p |= __shfl_xor(p, 2);
    p |= __shfl_xor(p, 4);

    if (bit == 0) {
        codes_g[b * (NPOS / 4) + s * 32 + j] = p;   // packed 4 codes / u32
        atomicAdd(&h[p & 255], 1);
        atomicAdd(&h[(p >> 8) & 255], 1);
        atomicAdd(&h[(p >> 16) & 255], 1);
        atomicAdd(&h[p >> 24], 1);
    }
    __syncthreads();

    partial_g[blk * NCODE + t] = h[t];   // full overwrite, no init needed
}

// ---------------------------------------------------------------------------
__global__ __launch_bounds__(1024) void k_table(const unsigned int* __restrict__ codes_g,
                                                const int* __restrict__ partial_g,
                                                const float* __restrict__ V,
                                                const float* __restrict__ temp,
                                                float* __restrict__ out) {
    const int b   = blockIdx.x >> 5;
    const int s   = blockIdx.x & (NSLICE - 1);
    const int tid = threadIdx.x;
    const int d   = tid >> 5;            // d-column owned by this half-wave
    const int l   = tid & 31;            // v-block: v = 8l..8l+7

    __shared__ float hq[4][NCODE];             // 4 KB partial sums (no atomics)
    __shared__ float hf[NCODE + NCODE / 8];    // padded: idx v + (v>>3)
    __shared__ float Sinv[NCODE + NCODE / 8];  // padded, same scheme
    __shared__ float T[NCODE * DV];            // 32 KB, swizzled (see below)

    // ---- sum the batch's 32 partial histograms (coalesced, L2-resident) ----
    {
        const int bin = tid & 255;
        const int q   = tid >> 8;              // 4 groups x 8 slices each
        const int* pg = partial_g + (b * NSLICE + q * 8) * NCODE + bin;
        int sum = 0;
#pragma unroll
        for (int i = 0; i < 8; ++i) sum += pg[i * NCODE];
        hq[q][bin] = (float)sum;
    }
    __syncthreads();
    if (tid < NCODE)
        hf[tid + (tid >> 3)] = hq[0][tid] + hq[1][tid] + hq[2][tid] + hq[3][tid];
    __syncthreads();

    const float a = __expf(-1.0f / fmaxf(temp[0], 0.1f));

    // ---- val seeds: hf reads at 9l+j are bank-conflict-free ----
    float val[8];
#pragma unroll
    for (int j = 0; j < 8; ++j) {
        const int v = l * 8 + j;
        val[j] = hf[9 * l + j] * V[v * DV + d];   // V is 32 KB -> cache-resident
    }

    // ---- val butterfly: stages 0..2 in registers ----
#pragma unroll
    for (int st = 0; st < 3; ++st) {
        const int m = 1 << st;
#pragma unroll
        for (int j = 0; j < 8; ++j) {
            if ((j & m) == 0) {
                const int j1 = j | m;
                const float v0 = val[j], v1 = val[j1];
                val[j]  = fmaf(a, v1, v0);
                val[j1] = fmaf(a, v0, v1);
            }
        }
    }
    // ---- val stages 3..7 via shuffle (masks 1..16 stay inside half-wave) ----
#pragma unroll
    for (int st = 0; st < 5; ++st) {
        const int m = 1 << st;
#pragma unroll
        for (int j = 0; j < 8; ++j) {
            const float pv = __shfl_xor(val[j], m);
            val[j] = fmaf(a, pv, val[j]);
        }
    }

    // ---- write unnormalized table; swizzle idx(c,d) = (c<<5) + (d ^ (c>>3))
    //      write bank = (d ^ l) % 32: all 32 lanes distinct -> conflict-free.
    {
        const int wbase = (l << 8) + (d ^ l);   // c = 8l+j -> c>>3 == l
#pragma unroll
        for (int j = 0; j < 8; ++j)
            T[wbase + (j << 5)] = val[j];
    }

    // ---- denominator butterfly: HALF-WAVE 0 ONLY (identical math, computed
    //      once instead of in all 32 d-columns). Shuffle partners l^m (m<=16)
    //      stay within active lanes 0..31 of wave 0. ----
    if (tid < 32) {
        float cnt[8];
#pragma unroll
        for (int j = 0; j < 8; ++j) cnt[j] = hf[9 * l + j];
#pragma unroll
        for (int st = 0; st < 3; ++st) {
            const int m = 1 << st;
#pragma unroll
            for (int j = 0; j < 8; ++j) {
                if ((j & m) == 0) {
                    const int j1 = j | m;
                    const float s0 = cnt[j], s1 = cnt[j1];
                    cnt[j]  = fmaf(a, s1, s0);
                    cnt[j1] = fmaf(a, s0, s1);
                }
            }
        }
#pragma unroll
        for (int st = 0; st < 5; ++st) {
            const int m = 1 << st;
#pragma unroll
            for (int j = 0; j < 8; ++j) {
                const float pc = __shfl_xor(cnt[j], m);
                cnt[j] = fmaf(a, pc, cnt[j]);
            }
        }
#pragma unroll
        for (int j = 0; j < 8; ++j) {
            const int c = l * 8 + j;
            Sinv[c + (c >> 3)] = 1.0f / cnt[j];   // S > 0 always (sum h = 4096)
        }
    }
    __syncthreads();

    // ---- gather own slice: one float4 store per thread ----
    {
        const int ng   = tid & 31;                 // float4 index within slice
        const int base = s * 128 + ng * 4;         // n offset of this float4
        const unsigned int cw = codes_g[b * (NPOS / 4) + s * 32 + ng];
        const int c0 = cw & 255, c1 = (cw >> 8) & 255,
                  c2 = (cw >> 16) & 255, c3 = cw >> 24;
        float4 r;
        r.x = T[(c0 << 5) + (d ^ (c0 >> 3))] * Sinv[c0 + (c0 >> 3)];
        r.y = T[(c1 << 5) + (d ^ (c1 >> 3))] * Sinv[c1 + (c1 >> 3)];
        r.z = T[(c2 << 5) + (d ^ (c2 >> 3))] * Sinv[c2 + (c2 >> 3)];
        r.w = T[(c3 << 5) + (d ^ (c3 >> 3))] * Sinv[c3 + (c3 >> 3)];
        float4* o4 = (float4*)(out + (size_t)(b * DV + d) * NPOS + base);
        *o4 = r;
    }
}

// ---------------------------------------------------------------------------
extern "C" void kernel_launch(void* const* d_in, const int* in_sizes, int n_in,
                              void* d_out, int out_size, void* d_ws, size_t ws_size,
                              hipStream_t stream) {
    const float* z    = (const float*)d_in[0];   // (B,8,64,64) fp32
    const float* temp = (const float*)d_in[1];   // scalar
    const float* V    = (const float*)d_in[2];   // (256,32) fp32
    float* out        = (float*)d_out;           // (B,32,64,64) fp32

    unsigned int* codes_g = (unsigned int*)d_ws;                    // 32 KB
    int* partial_g        = (int*)d_ws + B_SZ * (NPOS / 4);         // 256 KB

    k_codes<<<B_SZ * NSLICE, 256, 0, stream>>>(z, codes_g, partial_g);
    k_table<<<B_SZ * NSLICE, 1024, 0, stream>>>(codes_g, partial_g, V, temp, out);
}